// Round 3
// baseline (491.359 us; speedup 1.0000x reference)
//
#include <hip/hip_runtime.h>

#define FA 75
#define FB 12
#define CC 100
#define NN 20000
#define EE 40000
#define GG 1000
#define BN_EPS 1e-5f
#define ET 4   // edges per lane in msg_kernel

// workspace layout (float offsets)
#define OFF_W1P   0          // packed W1+b1: 7500 rows * 16 floats = 120000
#define OFF_S     0          // S[C,G] = 100000 floats, reuses W1p region AFTER msg
#define OFF_AGGT  120000     // aggT [C, N] = 2,000,000
#define OFF_HT    2120000    // h_t  [C, N] = 2,000,000
#define OFF_STAT  4120000    // mean[100] + rstd[100]
#define OFF_START 4120200    // int start[G+1]
// total ~4.13M floats ~= 16.5 MB

// Combined: pack W1+b1 into 16-float rows, and build molecule start offsets.
// W1p[r*16 + b] = W1[b*7500 + r] (b<12), W1p[r*16+12] = b1[r], rest 0.
__global__ __launch_bounds__(256) void prep_kernel(
    const float* __restrict__ W1, const float* __restrict__ b1,
    const int* __restrict__ batch,
    float* __restrict__ W1p, int* __restrict__ start)
{
    int idx = blockIdx.x * 256 + threadIdx.x;
    if (idx < 7500 * 16) {
        int r = idx >> 4, k = idx & 15;
        float v = 0.f;
        if (k < 12) v = W1[k * 7500 + r];
        else if (k == 12) v = b1[r];
        W1p[idx] = v;
    } else {
        int n = idx - 7500 * 16;
        if (n < NN) {
            int b = batch[n];
            int prev = (n == 0) ? -1 : batch[n - 1];
            for (int g = prev + 1; g <= b; ++g) start[g] = n;
            if (n == NN - 1)
                for (int g = b + 1; g <= GG; ++g) start[g] = NN;
        }
    }
}

// Fused NNConv message + scatter (channel-transposed agg).
// Each lane handles ET=4 consecutive edges; wave handles a uniform 5-channel
// group (cg 0..19). grid = ceil(E/256) * 5 blocks of 256 (4 waves).
// Scalar W1p row loads are reused across the 4 edge streams (4x compute per
// s_load vs R2) and the 4 streams give in-wave ILP over the x gathers.
__global__ __launch_bounds__(256) void msg_kernel(
    const float* __restrict__ x, const float* __restrict__ edge_attr,
    const float* __restrict__ W1p, const int* __restrict__ eidx,
    float* __restrict__ aggT)
{
    const int lane = threadIdx.x & 63;
    const int w = threadIdx.x >> 6;                    // 0..3
    const int eb = blockIdx.x / 5;
    const int cg = (blockIdx.x - eb * 5) * 4 + w;      // 0..19
    const int cbase = __builtin_amdgcn_readfirstlane(cg * 5);
    const int e0 = eb * 256 + lane * ET;

    int srce[ET], dste[ET];
    bool val[ET];
    const float* xp[ET];
    float4 ea0[ET], ea1[ET], ea2[ET];
#pragma unroll
    for (int t = 0; t < ET; ++t) {
        int e = e0 + t;
        val[t] = (e < EE);
        int ec = val[t] ? e : (EE - 1);
        srce[t] = eidx[ec];
        dste[t] = eidx[EE + ec];
        xp[t] = x + (size_t)srce[t] * FA;
        const float4* p = (const float4*)(edge_attr + (size_t)ec * FB);
        ea0[t] = p[0]; ea1[t] = p[1]; ea2[t] = p[2];
    }

    float acc[ET][5];
#pragma unroll
    for (int t = 0; t < ET; ++t)
#pragma unroll
        for (int j = 0; j < 5; ++j) acc[t][j] = 0.f;

    for (int i = 0; i < FA; ++i) {
        float xi[ET];
#pragma unroll
        for (int t = 0; t < ET; ++t) xi[t] = xp[t][i];

        const float* wb = W1p + (size_t)(i * CC + cbase) * 16;
#pragma unroll
        for (int j = 0; j < 5; ++j) {
            const float4* w4 = (const float4*)(wb + j * 16);
            float4 w0 = w4[0];
            float4 w1 = w4[1];
            float4 w2 = w4[2];
            float bb = wb[j * 16 + 12];   // b1
#pragma unroll
            for (int t = 0; t < ET; ++t) {
                float z = bb;
                z = fmaf(ea0[t].x, w0.x, z);
                z = fmaf(ea0[t].y, w0.y, z);
                z = fmaf(ea0[t].z, w0.z, z);
                z = fmaf(ea0[t].w, w0.w, z);
                z = fmaf(ea1[t].x, w1.x, z);
                z = fmaf(ea1[t].y, w1.y, z);
                z = fmaf(ea1[t].z, w1.z, z);
                z = fmaf(ea1[t].w, w1.w, z);
                z = fmaf(ea2[t].x, w2.x, z);
                z = fmaf(ea2[t].y, w2.y, z);
                z = fmaf(ea2[t].z, w2.z, z);
                z = fmaf(ea2[t].w, w2.w, z);
                z = fmaxf(z, 0.f);
                acc[t][j] = fmaf(xi[t], z, acc[t][j]);
            }
        }
    }

#pragma unroll
    for (int t = 0; t < ET; ++t) {
        if (val[t]) {
#pragma unroll
            for (int j = 0; j < 5; ++j)
                atomicAdd(&aggT[(size_t)(cbase + j) * NN + dste[t]], acc[t][j]);
        }
    }
}

// h_t[c][n] = relu(x @ W_root + aggT + bias), channel-transposed.
// lane = node; wave handles a uniform 10-channel group.
__global__ __launch_bounds__(128) void root_kernel(
    const float* __restrict__ x, const float* __restrict__ W_root,
    const float* __restrict__ bias, const float* __restrict__ aggT,
    float* __restrict__ h_t)
{
    const int lane = threadIdx.x & 63;
    const int w = threadIdx.x >> 6;                    // 0..1
    const int nb = blockIdx.x / 5;
    const int cg = (blockIdx.x - nb * 5) * 2 + w;      // 0..9
    const int cbase = __builtin_amdgcn_readfirstlane(cg * 10);
    const int n = nb * 64 + lane;
    const bool ok = (n < NN);
    const int nc = ok ? n : NN - 1;
    const float* xrow = x + (size_t)nc * FA;

    float acc[10];
#pragma unroll
    for (int j = 0; j < 10; ++j) acc[j] = 0.f;

    for (int i = 0; i < FA; ++i) {
        float xi = xrow[i];
        const float* wrow = W_root + i * CC + cbase;   // uniform -> s_load
#pragma unroll
        for (int j = 0; j < 10; ++j) acc[j] = fmaf(xi, wrow[j], acc[j]);
    }

    if (ok) {
#pragma unroll
        for (int j = 0; j < 10; ++j) {
            size_t off = (size_t)(cbase + j) * NN + n;
            h_t[off] = fmaxf(acc[j] + bias[cbase + j] + aggT[off], 0.f);
        }
    }
}

// Fused per-channel batch stats + per-(g,c) raw pool sums, one pass over h_t.
// block = channel c. Stats via float4 + double accumulation; pool sums reuse
// the L2-hot column.
__global__ __launch_bounds__(256) void reduce_kernel(
    const float* __restrict__ h_t, const int* __restrict__ start,
    float* __restrict__ S, float* __restrict__ stats)
{
    const int c = blockIdx.x;   // 0..99
    const float* col = h_t + (size_t)c * NN;
    const float4* row = (const float4*)col;
    double s = 0.0, s2 = 0.0;
    for (int k = threadIdx.x; k < NN / 4; k += 256) {
        float4 v = row[k];
        s += (double)v.x + (double)v.y + (double)v.z + (double)v.w;
        s2 += (double)v.x * v.x + (double)v.y * v.y
            + (double)v.z * v.z + (double)v.w * v.w;
    }
    __shared__ double sh[256];
    __shared__ double sh2[256];
    sh[threadIdx.x] = s;
    sh2[threadIdx.x] = s2;
    __syncthreads();
    for (int o = 128; o > 0; o >>= 1) {
        if (threadIdx.x < o) {
            sh[threadIdx.x] += sh[threadIdx.x + o];
            sh2[threadIdx.x] += sh2[threadIdx.x + o];
        }
        __syncthreads();
    }
    if (threadIdx.x == 0) {
        double mean = sh[0] / NN;
        double var = sh2[0] / NN - mean * mean;
        stats[c] = (float)mean;
        stats[CC + c] = 1.0f / sqrtf((float)var + BN_EPS);
    }
    // raw per-molecule sums (BN folded in algebraically in out_kernel)
    for (int g = threadIdx.x; g < GG; g += 256) {
        int n1 = start[g + 1];
        float sum = 0.f;
        for (int n = start[g]; n < n1; ++n) sum += col[n];
        S[(size_t)c * GG + g] = sum;
    }
}

// out[g] = relu(A_c*S[c,g] + cnt_g*(beta_c - A_c*mean_c)) . W_out + b_out
__global__ __launch_bounds__(128) void out_kernel(
    const float* __restrict__ S, const float* __restrict__ stats,
    const float* __restrict__ gamma, const float* __restrict__ beta,
    const int* __restrict__ start, const float* __restrict__ W_out,
    const float* __restrict__ b_out, float* __restrict__ out)
{
    const int g = blockIdx.x;
    const int c = threadIdx.x;
    float v = 0.f;
    if (c < CC) {
        float mean = stats[c], rstd = stats[CC + c];
        float A = gamma[c] * rstd;
        float B = beta[c] - A * mean;
        float cnt = (float)(start[g + 1] - start[g]);
        float pooled = fmaf(A, S[(size_t)c * GG + g], cnt * B);
        v = fmaxf(pooled, 0.f) * W_out[c];
    }
    __shared__ float sh[128];
    sh[threadIdx.x] = v;
    __syncthreads();
    for (int o = 64; o > 0; o >>= 1) {
        if (threadIdx.x < o) sh[threadIdx.x] += sh[threadIdx.x + o];
        __syncthreads();
    }
    if (threadIdx.x == 0) out[g] = sh[0] + b_out[0];
}

extern "C" void kernel_launch(void* const* d_in, const int* in_sizes, int n_in,
                              void* d_out, int out_size, void* d_ws, size_t ws_size,
                              hipStream_t stream)
{
    const float* x         = (const float*)d_in[0];
    const float* edge_attr = (const float*)d_in[1];
    const float* W1        = (const float*)d_in[2];
    const float* b1        = (const float*)d_in[3];
    const float* W_root    = (const float*)d_in[4];
    const float* bias      = (const float*)d_in[5];
    const float* gamma     = (const float*)d_in[6];
    const float* beta      = (const float*)d_in[7];
    const float* W_out     = (const float*)d_in[8];
    const float* b_out     = (const float*)d_in[9];
    const int*   eidx      = (const int*)d_in[10];
    const int*   batch     = (const int*)d_in[11];

    float* ws    = (float*)d_ws;
    float* W1p   = ws + OFF_W1P;
    float* S     = ws + OFF_S;      // aliases W1p; used only after msg
    float* aggT  = ws + OFF_AGGT;
    float* h_t   = ws + OFF_HT;
    float* stats = ws + OFF_STAT;
    int*   start = (int*)(ws + OFF_START);
    float* out   = (float*)d_out;

    hipMemsetAsync(aggT, 0, (size_t)NN * CC * sizeof(float), stream);

    prep_kernel<<<(7500 * 16 + NN + 255) / 256, 256, 0, stream>>>(W1, b1, batch, W1p, start);
    {
        int eblocks = (EE + 64 * ET - 1) / (64 * ET);   // 157
        msg_kernel<<<eblocks * 5, 256, 0, stream>>>(x, edge_attr, W1p, eidx, aggT);
    }
    root_kernel<<<((NN + 63) / 64) * 5, 128, 0, stream>>>(x, W_root, bias, aggT, h_t);
    reduce_kernel<<<CC, 256, 0, stream>>>(h_t, start, S, stats);
    out_kernel<<<GG, 128, 0, stream>>>(S, stats, gamma, beta, start, W_out, b_out, out);
}

// Round 4
// 419.716 us; speedup vs baseline: 1.1707x; 1.1707x over previous
//
#include <hip/hip_runtime.h>

#define FA 75
#define FB 12
#define CC 100
#define NN 20000
#define EE 40000
#define GG 1000
#define BN_EPS 1e-5f
#define XPAD 76   // x rows padded to 76 floats -> 304 B, 16-B aligned

// workspace layout (float offsets)
#define OFF_W1P   0          // packed W1+b1: 7500 rows * 16 floats = 120000
#define OFF_S     0          // S[C,G] = 100000, reuses W1p region AFTER msg
#define OFF_XP    120000     // padded x [N][76] = 1,520,000
#define OFF_AGGT  1640000    // aggT [C, N] = 2,000,000
#define OFF_HT    3640000    // h_t  [C, N] = 2,000,000
#define OFF_STAT  5640000    // mean[100] + rstd[100]
#define OFF_START 5640200    // int start[G+1]
// total ~5.65M floats ~= 22.6 MB

// prep: (a) pack W1+b1 into 16-float rows, (b) molecule start offsets,
// (c) pad-pack x into 76-float (16B-aligned) rows for float4 gathers.
__global__ __launch_bounds__(256) void prep_kernel(
    const float* __restrict__ W1, const float* __restrict__ b1,
    const float* __restrict__ x, const int* __restrict__ batch,
    float* __restrict__ W1p, float* __restrict__ xp, int* __restrict__ start)
{
    int idx = blockIdx.x * 256 + threadIdx.x;
    if (idx < 120000) {
        int r = idx >> 4, k = idx & 15;
        float v = 0.f;
        if (k < 12) v = W1[k * 7500 + r];
        else if (k == 12) v = b1[r];
        W1p[idx] = v;
    } else if (idx < 140000) {
        int n = idx - 120000;
        int b = batch[n];
        int prev = (n == 0) ? -1 : batch[n - 1];
        for (int g = prev + 1; g <= b; ++g) start[g] = n;
        if (n == NN - 1)
            for (int g = b + 1; g <= GG; ++g) start[g] = NN;
    } else {
        int t = idx - 140000;
        if (t < NN * XPAD) {
            int n = t / XPAD;
            int i = t - n * XPAD;
            xp[t] = (i < FA) ? x[n * FA + i] : 0.f;
        }
    }
}

// Fused NNConv message + scatter (channel-transposed agg).
// lane = edge; wave = uniform 10-channel group (cg 0..9).
// block = 320 thr (5 waves = 5 cgs); grid = 625 edge-groups * 2.
// x[src] row preloaded into registers as 19 float4 gathers (one pipelined
// burst) -> K-loop is pure VALU + uniform s_loads of W1p.
__global__ __launch_bounds__(320) void msg_kernel(
    const float* __restrict__ xp, const float* __restrict__ edge_attr,
    const float* __restrict__ W1p, const int* __restrict__ eidx,
    float* __restrict__ aggT)
{
    const int lane = threadIdx.x & 63;
    const int w = threadIdx.x >> 6;                    // 0..4
    const int eb = blockIdx.x >> 1;
    const int cg = (blockIdx.x & 1) * 5 + w;           // 0..9
    const int cbase = __builtin_amdgcn_readfirstlane(cg * 10);
    const int e = eb * 64 + lane;
    const int src = eidx[e];
    const int dst = eidx[EE + e];

    const float4* ea4 = (const float4*)(edge_attr + (size_t)e * FB);
    float4 a0 = ea4[0], a1 = ea4[1], a2 = ea4[2];

    const float4* xr4 = (const float4*)(xp + (size_t)src * XPAD);

    float acc[10];
#pragma unroll
    for (int j = 0; j < 10; ++j) acc[j] = 0.f;

    float4 cur = xr4[0];
#pragma unroll 1
    for (int k = 0; k < 18; ++k) {
        float4 nxt = xr4[k + 1];                       // prefetch next chunk
        float xiv[4] = {cur.x, cur.y, cur.z, cur.w};
        const float* wb0 = W1p + ((size_t)(k * 4) * CC + cbase) * 16;
#pragma unroll
        for (int u = 0; u < 4; ++u) {
            const float* wb = wb0 + (size_t)u * CC * 16;
#pragma unroll
            for (int j = 0; j < 10; ++j) {
                const float4* w4 = (const float4*)(wb + j * 16);
                float4 w0 = w4[0];
                float4 w1 = w4[1];
                float4 w2 = w4[2];
                float z = wb[j * 16 + 12];             // b1
                z = fmaf(a0.x, w0.x, z);
                z = fmaf(a0.y, w0.y, z);
                z = fmaf(a0.z, w0.z, z);
                z = fmaf(a0.w, w0.w, z);
                z = fmaf(a1.x, w1.x, z);
                z = fmaf(a1.y, w1.y, z);
                z = fmaf(a1.z, w1.z, z);
                z = fmaf(a1.w, w1.w, z);
                z = fmaf(a2.x, w2.x, z);
                z = fmaf(a2.y, w2.y, z);
                z = fmaf(a2.z, w2.z, z);
                z = fmaf(a2.w, w2.w, z);
                z = fmaxf(z, 0.f);
                acc[j] = fmaf(xiv[u], z, acc[j]);
            }
        }
        cur = nxt;
    }
    {   // tail: i = 72, 73, 74
        float xiv[3] = {cur.x, cur.y, cur.z};
        const float* wb0 = W1p + ((size_t)(72) * CC + cbase) * 16;
#pragma unroll
        for (int u = 0; u < 3; ++u) {
            const float* wb = wb0 + (size_t)u * CC * 16;
#pragma unroll
            for (int j = 0; j < 10; ++j) {
                const float4* w4 = (const float4*)(wb + j * 16);
                float4 w0 = w4[0];
                float4 w1 = w4[1];
                float4 w2 = w4[2];
                float z = wb[j * 16 + 12];
                z = fmaf(a0.x, w0.x, z);
                z = fmaf(a0.y, w0.y, z);
                z = fmaf(a0.z, w0.z, z);
                z = fmaf(a0.w, w0.w, z);
                z = fmaf(a1.x, w1.x, z);
                z = fmaf(a1.y, w1.y, z);
                z = fmaf(a1.z, w1.z, z);
                z = fmaf(a1.w, w1.w, z);
                z = fmaf(a2.x, w2.x, z);
                z = fmaf(a2.y, w2.y, z);
                z = fmaf(a2.z, w2.z, z);
                z = fmaf(a2.w, w2.w, z);
                z = fmaxf(z, 0.f);
                acc[j] = fmaf(xiv[u], z, acc[j]);
            }
        }
    }

#pragma unroll
    for (int j = 0; j < 10; ++j)
        atomicAdd(&aggT[(size_t)(cbase + j) * NN + dst], acc[j]);
}

// h_t[c][n] = relu(x @ W_root + aggT + bias), channel-transposed.
// lane = node; wave = uniform 10-channel group; xp-row register preload.
__global__ __launch_bounds__(128) void root_kernel(
    const float* __restrict__ xp, const float* __restrict__ W_root,
    const float* __restrict__ bias, const float* __restrict__ aggT,
    float* __restrict__ h_t)
{
    const int lane = threadIdx.x & 63;
    const int w = threadIdx.x >> 6;                    // 0..1
    const int nb = blockIdx.x / 5;
    const int cg = (blockIdx.x - nb * 5) * 2 + w;      // 0..9
    const int cbase = __builtin_amdgcn_readfirstlane(cg * 10);
    const int n = nb * 64 + lane;
    const bool ok = (n < NN);
    const int nc = ok ? n : NN - 1;
    const float4* xr4 = (const float4*)(xp + (size_t)nc * XPAD);

    float acc[10];
#pragma unroll
    for (int j = 0; j < 10; ++j) acc[j] = 0.f;

    float4 cur = xr4[0];
#pragma unroll 1
    for (int k = 0; k < 18; ++k) {
        float4 nxt = xr4[k + 1];
        float xiv[4] = {cur.x, cur.y, cur.z, cur.w};
#pragma unroll
        for (int u = 0; u < 4; ++u) {
            const float* wrow = W_root + (k * 4 + u) * CC + cbase;  // s_load
#pragma unroll
            for (int j = 0; j < 10; ++j) acc[j] = fmaf(xiv[u], wrow[j], acc[j]);
        }
        cur = nxt;
    }
    {
        float xiv[3] = {cur.x, cur.y, cur.z};
#pragma unroll
        for (int u = 0; u < 3; ++u) {
            const float* wrow = W_root + (72 + u) * CC + cbase;
#pragma unroll
            for (int j = 0; j < 10; ++j) acc[j] = fmaf(xiv[u], wrow[j], acc[j]);
        }
    }

    if (ok) {
#pragma unroll
        for (int j = 0; j < 10; ++j) {
            size_t off = (size_t)(cbase + j) * NN + n;
            h_t[off] = fmaxf(acc[j] + bias[cbase + j] + aggT[off], 0.f);
        }
    }
}

// Fused per-channel batch stats + per-(g,c) raw pool sums, one pass over h_t.
__global__ __launch_bounds__(256) void reduce_kernel(
    const float* __restrict__ h_t, const int* __restrict__ start,
    float* __restrict__ S, float* __restrict__ stats)
{
    const int c = blockIdx.x;   // 0..99
    const float* col = h_t + (size_t)c * NN;
    const float4* row = (const float4*)col;
    double s = 0.0, s2 = 0.0;
    for (int k = threadIdx.x; k < NN / 4; k += 256) {
        float4 v = row[k];
        s += (double)v.x + (double)v.y + (double)v.z + (double)v.w;
        s2 += (double)v.x * v.x + (double)v.y * v.y
            + (double)v.z * v.z + (double)v.w * v.w;
    }
    __shared__ double sh[256];
    __shared__ double sh2[256];
    sh[threadIdx.x] = s;
    sh2[threadIdx.x] = s2;
    __syncthreads();
    for (int o = 128; o > 0; o >>= 1) {
        if (threadIdx.x < o) {
            sh[threadIdx.x] += sh[threadIdx.x + o];
            sh2[threadIdx.x] += sh2[threadIdx.x + o];
        }
        __syncthreads();
    }
    if (threadIdx.x == 0) {
        double mean = sh[0] / NN;
        double var = sh2[0] / NN - mean * mean;
        stats[c] = (float)mean;
        stats[CC + c] = 1.0f / sqrtf((float)var + BN_EPS);
    }
    for (int g = threadIdx.x; g < GG; g += 256) {
        int n1 = start[g + 1];
        float sum = 0.f;
        for (int n = start[g]; n < n1; ++n) sum += col[n];
        S[(size_t)c * GG + g] = sum;
    }
}

// out[g] = relu(A_c*S[c,g] + cnt_g*(beta_c - A_c*mean_c)) . W_out + b_out
__global__ __launch_bounds__(128) void out_kernel(
    const float* __restrict__ S, const float* __restrict__ stats,
    const float* __restrict__ gamma, const float* __restrict__ beta,
    const int* __restrict__ start, const float* __restrict__ W_out,
    const float* __restrict__ b_out, float* __restrict__ out)
{
    const int g = blockIdx.x;
    const int c = threadIdx.x;
    float v = 0.f;
    if (c < CC) {
        float mean = stats[c], rstd = stats[CC + c];
        float A = gamma[c] * rstd;
        float B = beta[c] - A * mean;
        float cnt = (float)(start[g + 1] - start[g]);
        float pooled = fmaf(A, S[(size_t)c * GG + g], cnt * B);
        v = fmaxf(pooled, 0.f) * W_out[c];
    }
    __shared__ float sh[128];
    sh[threadIdx.x] = v;
    __syncthreads();
    for (int o = 64; o > 0; o >>= 1) {
        if (threadIdx.x < o) sh[threadIdx.x] += sh[threadIdx.x + o];
        __syncthreads();
    }
    if (threadIdx.x == 0) out[g] = sh[0] + b_out[0];
}

extern "C" void kernel_launch(void* const* d_in, const int* in_sizes, int n_in,
                              void* d_out, int out_size, void* d_ws, size_t ws_size,
                              hipStream_t stream)
{
    const float* x         = (const float*)d_in[0];
    const float* edge_attr = (const float*)d_in[1];
    const float* W1        = (const float*)d_in[2];
    const float* b1        = (const float*)d_in[3];
    const float* W_root    = (const float*)d_in[4];
    const float* bias      = (const float*)d_in[5];
    const float* gamma     = (const float*)d_in[6];
    const float* beta      = (const float*)d_in[7];
    const float* W_out     = (const float*)d_in[8];
    const float* b_out     = (const float*)d_in[9];
    const int*   eidx      = (const int*)d_in[10];
    const int*   batch     = (const int*)d_in[11];

    float* ws    = (float*)d_ws;
    float* W1p   = ws + OFF_W1P;
    float* S     = ws + OFF_S;      // aliases W1p; used only after msg
    float* xp    = ws + OFF_XP;
    float* aggT  = ws + OFF_AGGT;
    float* h_t   = ws + OFF_HT;
    float* stats = ws + OFF_STAT;
    int*   start = (int*)(ws + OFF_START);
    float* out   = (float*)d_out;

    hipMemsetAsync(aggT, 0, (size_t)NN * CC * sizeof(float), stream);

    {
        int total = 140000 + NN * XPAD;
        prep_kernel<<<(total + 255) / 256, 256, 0, stream>>>(
            W1, b1, x, batch, W1p, xp, start);
    }
    msg_kernel<<<(EE / 64) * 2, 320, 0, stream>>>(xp, edge_attr, W1p, eidx, aggT);
    root_kernel<<<((NN + 63) / 64) * 5, 128, 0, stream>>>(xp, W_root, bias, aggT, h_t);
    reduce_kernel<<<CC, 256, 0, stream>>>(h_t, start, S, stats);
    out_kernel<<<GG, 128, 0, stream>>>(S, stats, gamma, beta, start, W_out, b_out, out);
}